// Round 14
// baseline (172.748 us; speedup 1.0000x reference)
//
#include <hip/hip_runtime.h>
#include <hip/hip_bf16.h>

typedef __attribute__((ext_vector_type(8))) short short8;
typedef __attribute__((ext_vector_type(4))) float floatx4;

struct ushort4v { unsigned short x, y, z, w; };

static __device__ __forceinline__ unsigned short f2bf(float f) {
    __hip_bfloat16 h = __float2bfloat16(f);
    return *reinterpret_cast<unsigned short*>(&h);
}

static __device__ __forceinline__ float bf2f(unsigned short u) {
    unsigned int v = ((unsigned int)u) << 16;
    return *reinterpret_cast<float*>(&v);
}

#define ASYNC_COPY16(gsrc, ldst)                                                            \
    __builtin_amdgcn_global_load_lds((const __attribute__((address_space(1))) void*)(gsrc), \
                                     (__attribute__((address_space(3))) void*)(ldst), 16, 0, 0)

static __device__ __forceinline__ void block_barrier() {
    asm volatile("" ::: "memory");
    __builtin_amdgcn_s_barrier();
    asm volatile("" ::: "memory");
}

// ---------------------------------------------------------------------------
// fused mask kernel: each block re-derives the bool encoding (u8 vs i32) from
// the first 8KB (L2-hot after block 0), then expands its slice.
// keep[i] = 1.0f attended, 0.0f masked row (exp(score*0)=1 -> uniform softmax,
// identical to reference where score/32 + (-1e9) rounds to exactly -1e9).
// ---------------------------------------------------------------------------
__global__ __launch_bounds__(256) void mask_expand_fused(const unsigned char* __restrict__ m,
                                                         float* __restrict__ keep, int n) {
    __shared__ int s_or;
    if (threadIdx.x == 0) s_or = 0;
    __syncthreads();
    int acc = 0;
    for (int i = threadIdx.x; i < 8192; i += 256)
        if (i & 3) acc |= m[i];
    atomicOr(&s_or, acc);
    __syncthreads();
    const bool u8enc = (s_or != 0);
    int i = blockIdx.x * 256 + threadIdx.x;
    if (i < n) {
        bool on = u8enc ? (m[i] != 0) : (((const int*)m)[i] != 0);
        keep[i] = on ? 1.0f : 0.0f;
    }
}

// ---------------------------------------------------------------------------
__global__ __launch_bounds__(256) void convert_f32_bf16(const float* __restrict__ in,
                                                        unsigned short* __restrict__ out, long n4) {
    long i = (long)blockIdx.x * 256 + threadIdx.x;
    if (i >= n4) return;
    float4 v = ((const float4*)in)[i];
    ushort4v o;
    o.x = f2bf(v.x); o.y = f2bf(v.y); o.z = f2bf(v.z); o.w = f2bf(v.w);
    ((ushort4v*)out)[i] = o;
}

// ---------------------------------------------------------------------------
__global__ void transpose_w_kernel(const float* __restrict__ w0, const float* __restrict__ w1,
                                   const float* __restrict__ w2, unsigned short* __restrict__ out) {
    __shared__ float t[32][33];
    const float* w = blockIdx.z == 0 ? w0 : (blockIdx.z == 1 ? w1 : w2);
    unsigned short* o = out + (long)blockIdx.z * 1024 * 1024;
    int c0 = blockIdx.x * 32, r0 = blockIdx.y * 32;
    for (int i = threadIdx.y; i < 32; i += 8)
        t[i][threadIdx.x] = w[(long)(r0 + i) * 1024 + c0 + threadIdx.x];
    __syncthreads();
    for (int i = threadIdx.y; i < 32; i += 8)
        o[(long)(c0 + i) * 1024 + r0 + threadIdx.x] = f2bf(t[threadIdx.x][i]);
}

// ---------------------------------------------------------------------------
// Ring GEMM (round-8 proven): C[M,N] = A[M,K] * BT[N,K]^T  (bf16, fp32 accum)
// 128x256 tile, BK=32, 8 waves, depth-3 LDS ring (72KB -> 2 blocks/CU),
// one barrier per K-step, counted vmcnt(3)/(0), 64B-row swizzle both sides.
// EPI 0: QKV — z<2 store bf16 C; z==2 store V TRANSPOSED to vt via LDS.
// EPI 1: bf16 exp(acc*scale*keep[row]).
// EPI 2: PV — in-kernel ROW SUMS of A (=unnormalized P): PV's K axis is the
//   softmax axis and each block streams its rows' FULL length, so wn==0 waves
//   accumulate sum(af) per lane (lane fr = row, fk = k-octet -> every k
//   counted once), shfl-reduce across fk, redistribute via 512B of ring LDS;
//   epilogue stores acc / rowsum[row]. Replaces the separate rowsum pass.
// ---------------------------------------------------------------------------
template <int EPI>
static __device__ __forceinline__ void gemm8_body(const unsigned short* __restrict__ A,
                                                  const unsigned short* __restrict__ B,
                                                  void* __restrict__ Cv,
                                                  unsigned short* __restrict__ vt,
                                                  const float* __restrict__ aux,
                                                  int K, int lda, int ldb, int ldc,
                                                  long sA, long sB, long sC, long sAux,
                                                  float scale) {
    constexpr int TILE = (128 + 256) * 32 * 2;  // 24576 B per K-tile (A+B)
    __shared__ char sm[3 * TILE];

    const int tid = threadIdx.x;
    const int wid = tid >> 6, lane = tid & 63;
    const int wm  = wid >> 2, wn = wid & 3;       // 2 x 4 wave grid
    const int fr  = lane & 15, fk = lane >> 4;
    const long m0 = (long)blockIdx.x * 128;
    const long n0 = (long)blockIdx.y * 256;
    const unsigned short* Ab = A + (long)blockIdx.z * sA + m0 * lda;
    const unsigned short* Bb = B + (long)blockIdx.z * sB + n0 * ldb;
    const int NT = K >> 5;

    floatx4 acc[4][4] = {};
    float rsum[4] = {0.f, 0.f, 0.f, 0.f};   // EPI==2, wn==0: row-sum accum

    auto stage = [&](int kt, int buf) {
        char* dA = sm + buf * TILE;
        char* dB = dA + 128 * 64;                 // A part = 8192 B
        const int kb = kt << 5;
        {
            int lam = tid * 16;
            int lg  = lam ^ (((lam >> 7) & 3) << 4);
            ASYNC_COPY16(Ab + (long)(lg >> 6) * lda + kb + ((lg & 63) >> 1), dA + lam);
        }
#pragma unroll
        for (int i = 0; i < 2; i++) {
            int lam = i * 8192 + tid * 16;
            int lg  = lam ^ (((lam >> 7) & 3) << 4);
            ASYNC_COPY16(Bb + (long)(lg >> 6) * ldb + kb + ((lg & 63) >> 1), dB + lam);
        }
    };

    stage(0, 0);
    stage(1, 1);

    int cur = 0;
    for (int t = 0; t < NT; t++) {
        if (t + 1 < NT) asm volatile("s_waitcnt vmcnt(3)" ::: "memory");
        else            asm volatile("s_waitcnt vmcnt(0)" ::: "memory");
        block_barrier();   // after this, every wave's reads of tile t-1 returned

        const char* bA = sm + cur * TILE;
        const char* bB = bA + 128 * 64;
        short8 af[4], bf[4];
#pragma unroll
        for (int mi = 0; mi < 4; mi++) {
            int row = wm * 64 + mi * 16 + fr;
            int c   = (fk * 16) ^ (((row >> 1) & 3) << 4);
            af[mi] = *(const short8*)(bA + row * 64 + c);
        }
#pragma unroll
        for (int ni = 0; ni < 4; ni++) {
            int row = wn * 64 + ni * 16 + fr;
            int c   = (fk * 16) ^ (((row >> 1) & 3) << 4);
            bf[ni] = *(const short8*)(bB + row * 64 + c);
        }
        if (t + 2 < NT) stage(t + 2, (cur + 2) % 3);   // refill buf freed at this barrier

        if (EPI == 2 && wn == 0) {
#pragma unroll
            for (int mi = 0; mi < 4; mi++)
#pragma unroll
                for (int j = 0; j < 8; j++)
                    rsum[mi] += bf2f((unsigned short)af[mi][j]);
        }

        __builtin_amdgcn_s_setprio(1);
#pragma unroll
        for (int mi = 0; mi < 4; mi++)
#pragma unroll
            for (int ni = 0; ni < 4; ni++)
                acc[mi][ni] = __builtin_amdgcn_mfma_f32_16x16x32_bf16(af[mi], bf[ni], acc[mi][ni], 0, 0, 0);
        __builtin_amdgcn_s_setprio(0);
        cur = (cur == 2) ? 0 : cur + 1;
    }

    const int crow = (lane >> 4) * 4;
    const int ccol = lane & 15;

    if (EPI == 0 && blockIdx.z == 2) {
        // V projection: emit TRANSPOSED via LDS. T[256 d][132 pad] bf16 = 67.6KB.
        block_barrier();   // all waves done with ring LDS
        unsigned short* T = (unsigned short*)sm;
        constexpr int LDT = 132;
#pragma unroll
        for (int mi = 0; mi < 4; mi++)
#pragma unroll
            for (int j = 0; j < 4; j++) {
                int rl = wm * 64 + mi * 16 + crow + j;      // s-local (0..127)
#pragma unroll
                for (int ni = 0; ni < 4; ni++) {
                    int cl = wn * 64 + ni * 16 + ccol;      // d-local (0..255)
                    T[cl * LDT + rl] = f2bf(acc[mi][ni][j]);
                }
            }
        block_barrier();
        // store Vt[b][d][s]: batch-decompose the flattened M index
        const long bb   = m0 >> 11;              // batch = m0 / 2048
        const long sloc = m0 & 2047;             // s offset within batch
        unsigned short* vb = vt + bb * (1024L * 2048) + sloc;
#pragma unroll
        for (int p = 0; p < 8; p++) {
            int chunk = p * 512 + tid;            // 0..4095
            int d  = chunk >> 4;                  // 256 rows x 16 chunks of 8
            int s0 = (chunk & 15) * 8;
            short8 v = *(const short8*)&T[d * LDT + s0];
            *(short8*)(vb + (n0 + d) * 2048 + s0) = v;
        }
        return;
    }

    float* rs = (float*)sm;   // EPI==2: 128 row-sums in freed ring LDS
    if (EPI == 2) {
        block_barrier();      // all waves done reading ring LDS
        if (wn == 0) {
#pragma unroll
            for (int mi = 0; mi < 4; mi++) {
                float s = rsum[mi];
                s += __shfl_xor(s, 16);
                s += __shfl_xor(s, 32);          // all 4 fk-lanes now hold total
                if ((lane >> 4) == 0) rs[wm * 64 + mi * 16 + fr] = s;
            }
        }
        block_barrier();
    }

#pragma unroll
    for (int mi = 0; mi < 4; mi++) {
#pragma unroll
        for (int j = 0; j < 4; j++) {
            long r = m0 + wm * 64 + mi * 16 + crow + j;
            float rowf = 0.0f;
            if (EPI == 1) rowf = scale * aux[(long)blockIdx.z * sAux + r];       // scale*keep
            if (EPI == 2) rowf = 1.0f / rs[wm * 64 + mi * 16 + crow + j];        // 1/rowsum
#pragma unroll
            for (int ni = 0; ni < 4; ni++) {
                long c = n0 + wn * 64 + ni * 16 + ccol;
                float v = acc[mi][ni][j];
                if (EPI == 0) {
                    ((unsigned short*)Cv)[(long)blockIdx.z * sC + r * ldc + c] = f2bf(v);
                } else if (EPI == 1) {
                    ((unsigned short*)Cv)[(long)blockIdx.z * sC + r * ldc + c] = f2bf(__expf(v * rowf));
                } else {
                    ((float*)Cv)[(long)blockIdx.z * sC + r * ldc + c] = v * rowf;
                }
            }
        }
    }
}

__global__ __launch_bounds__(512, 4) void gemm8_qkv(const unsigned short* __restrict__ A,
                                                    const unsigned short* __restrict__ B,
                                                    void* __restrict__ Cv,
                                                    unsigned short* __restrict__ vt,
                                                    int K, int lda, int ldb, int ldc,
                                                    long sA, long sB, long sC) {
    gemm8_body<0>(A, B, Cv, vt, nullptr, K, lda, ldb, ldc, sA, sB, sC, 0L, 1.0f);
}

__global__ __launch_bounds__(512, 4) void gemm8_scores(const unsigned short* __restrict__ A,
                                                       const unsigned short* __restrict__ B,
                                                       void* __restrict__ Cv,
                                                       const float* __restrict__ keep,
                                                       int K, int lda, int ldb, int ldc,
                                                       long sA, long sB, long sC, long sAux,
                                                       float scale) {
    gemm8_body<1>(A, B, Cv, nullptr, keep, K, lda, ldb, ldc, sA, sB, sC, sAux, scale);
}

__global__ __launch_bounds__(512, 4) void gemm8_pv(const unsigned short* __restrict__ A,
                                                   const unsigned short* __restrict__ B,
                                                   void* __restrict__ Cv,
                                                   int K, int lda, int ldb, int ldc,
                                                   long sA, long sB, long sC) {
    gemm8_body<2>(A, B, Cv, nullptr, nullptr, K, lda, ldb, ldc, sA, sB, sC, 0L, 1.0f);
}

// ---------------------------------------------------------------------------
extern "C" void kernel_launch(void* const* d_in, const int* in_sizes, int n_in,
                              void* d_out, int out_size, void* d_ws, size_t ws_size,
                              hipStream_t stream) {
    const float* x  = (const float*)d_in[0];
    const void*  mask = d_in[1];
    const float* qw = (const float*)d_in[2];
    const float* kw = (const float*)d_in[3];
    const float* vw = (const float*)d_in[4];
    float* out = (float*)d_out;

    constexpr int B = 4, S = 2048, D = 1024;
    constexpr long BS  = (long)B * S;      // 8192
    constexpr long BSD = BS * D;           // 8388608

    char* w = (char*)d_ws;
    auto alloc = [&](size_t bytes) {
        char* p = w;
        w += (bytes + 255) & ~(size_t)255;
        return p;
    };
    float*          keep    = (float*)alloc(BS * 4);
    unsigned short* xb      = (unsigned short*)alloc((size_t)BSD * 2);
    unsigned short* wT      = (unsigned short*)alloc((size_t)3 * D * D * 2);
    unsigned short* qk      = (unsigned short*)alloc((size_t)2 * BSD * 2);  // Q,K slabs
    unsigned short* Qb = qk;
    unsigned short* Kb = qk + BSD;
    unsigned short* Vt      = (unsigned short*)alloc((size_t)BSD * 2);      // V transposed [b][d][s]

    size_t base_used = (size_t)(w - (char*)d_ws);
    size_t pB = (size_t)B * S * S * 2;  // 32 MiB unnormalized P (bf16)
    bool batched = ws_size >= base_used + pB + 1024;

    unsigned short* P;
    if (batched) {
        P = (unsigned short*)alloc(pB);
    } else {
        P = (unsigned short*)alloc((size_t)S * S * 2);
    }

    const float scale = 0.03125f;  // 1/sqrt(1024), exact

    mask_expand_fused<<<(int)(BS / 256), 256, 0, stream>>>((const unsigned char*)mask, keep, (int)BS);
    convert_f32_bf16<<<(int)(BSD / 1024), 256, 0, stream>>>(x, xb, BSD / 4);
    transpose_w_kernel<<<dim3(32, 32, 3), dim3(32, 8), 0, stream>>>(qw, kw, vw, wT);

    // Q,K,V projections: z<2 -> qk slabs; z==2 -> Vt (transposed in-epilogue)
    gemm8_qkv<<<dim3(64, 4, 3), 512, 0, stream>>>(xb, wT, qk, Vt,
                                                  1024, 1024, 1024, 1024,
                                                  0L, (long)D * D, BSD);

    if (batched) {
        // P = exp(QK^T * scale * keep), bf16  (512 blocks = one 2/CU round)
        gemm8_scores<<<dim3(16, 8, B), 512, 0, stream>>>(Qb, Kb, P, keep,
                                                         1024, 1024, 1024, 2048,
                                                         (long)S * D, (long)S * D, (long)S * S, (long)S, scale);
        // out = (P / rowsum) . V — rowsum computed in-kernel (8-wave ring)
        gemm8_pv<<<dim3(16, 4, B), 512, 0, stream>>>(P, Vt, out,
                                                     2048, 2048, 2048, 1024,
                                                     (long)S * S, (long)D * S, (long)S * D);
    } else {
        for (int b = 0; b < B; b++) {
            gemm8_scores<<<dim3(16, 8, 1), 512, 0, stream>>>(Qb + (long)b * S * D, Kb + (long)b * S * D,
                                                             P, keep + (long)b * S,
                                                             1024, 1024, 1024, 2048,
                                                             0L, 0L, 0L, 0L, scale);
            gemm8_pv<<<dim3(16, 4, 1), 512, 0, stream>>>(P, Vt + (long)b * D * S, out + (long)b * S * D,
                                                         2048, 2048, 2048, 1024,
                                                         0L, 0L, 0L);
        }
    }
}